// Round 14
// baseline (826.049 us; speedup 1.0000x reference)
//
#include <hip/hip_runtime.h>

#define T_STEPS 800
#define NBATCH  32
#define SST     1024
#define ROW     5120            // floats per (t, n) row
#define STRIDE  (NBATCH * ROW)  // floats between consecutive t rows
#define NSLOT   4               // LDS ring slots
#define ARMY_F  96
#define ARMY_B  96

__device__ __forceinline__ float lse5(float v0, float v1, float v2, float v3, float v4) {
  float m = fmaxf(fmaxf(fmaxf(v0, v1), fmaxf(v2, v3)), v4);
  float s = __expf(v0 - m) + __expf(v1 - m) + __expf(v2 - m) +
            __expf(v3 - m) + __expf(v4 - m);
  return m + __logf(s);
}

#define WAITVM(N) do { \
  asm volatile("s_waitcnt vmcnt(" #N ")" ::: "memory"); \
  __builtin_amdgcn_sched_barrier(0); } while (0)

// Block barrier draining LDS ops only; global traffic stays in flight.
__device__ __forceinline__ void barrier_lgkm() {
  asm volatile("s_waitcnt lgkmcnt(0)" ::: "memory");
  __builtin_amdgcn_s_barrier();
  asm volatile("" ::: "memory");
}

// ---------------- loader waves (waves 4..7 of scan blocks) ----------------
// Loader l owns floats [1280l, 1280l+1280) of each row. Pipeline: 3 row-sets
// of 5 NAMED float4 regs. At step s: issue row s+3, cert row s+2, ds_write it
// (+ fwd: store out0 row from the same regs).
template <int DIR>
__device__ void loader_run(const float* __restrict__ base,
                           float* __restrict__ out0n, int l, int lane,
                           float* __restrict__ ring) {
  const int loff = 1280 * l + 4 * lane;
  const ptrdiff_t str = DIR ? -(ptrdiff_t)STRIDE : (ptrdiff_t)STRIDE;
  const float* gIss = base + (size_t)(DIR ? (T_STEPS - 1) * STRIDE : 0) + loff;
  float* ringl = ring + loff;

  float4 A0, A1, A2, A3, A4, B0, B1, B2, B3, B4, C0, C1, C2, C3, C4;

#define LOADSET(R0,R1,R2,R3,R4) do { \
    const float4* gp_ = (const float4*)gIss; \
    R0 = gp_[0]; R1 = gp_[64]; R2 = gp_[128]; R3 = gp_[192]; R4 = gp_[256]; \
    gIss += str; } while (0)

#define WRITESET(R0,R1,R2,R3,R4) do { \
    float4* lw_ = (float4*)lsWr; \
    lw_[0] = R0; lw_[64] = R1; lw_[128] = R2; lw_[192] = R3; lw_[256] = R4; \
    if constexpr (!DIR) { \
      float4* op_ = (float4*)oSt; \
      op_[0] = R0; op_[64] = R1; op_[128] = R2; op_[192] = R3; op_[256] = R4; \
      oSt += ROW; } \
    wslot = (wslot + 1) & (NSLOT - 1); \
    lsWr = ringl + wslot * ROW; } while (0)

  LOADSET(A0,A1,A2,A3,A4);
  LOADSET(B0,B1,B2,B3,B4);
  LOADSET(C0,C1,C2,C3,C4);
  int wslot = 0;
  float* lsWr = ringl;
  float* oSt = out0n + loff;
  WAITVM(10);
  WRITESET(A0,A1,A2,A3,A4);
  if constexpr (!DIR) { WAITVM(10); } else { WAITVM(5); }
  WRITESET(B0,B1,B2,B3,B4);
  barrier_lgkm();

#define LSTEP(I0,I1,I2,I3,I4, W0,W1,W2,W3,W4) do { \
    LOADSET(I0,I1,I2,I3,I4); \
    if constexpr (!DIR) { WAITVM(10); } else { WAITVM(5); } \
    WRITESET(W0,W1,W2,W3,W4); \
    barrier_lgkm(); } while (0)

  for (int c = 0; c < 265; ++c) {
    LSTEP(A0,A1,A2,A3,A4, C0,C1,C2,C3,C4);
    LSTEP(B0,B1,B2,B3,B4, A0,A1,A2,A3,A4);
    LSTEP(C0,C1,C2,C3,C4, B0,B1,B2,B3,B4);
  }
  LSTEP(A0,A1,A2,A3,A4, C0,C1,C2,C3,C4);
  LSTEP(B0,B1,B2,B3,B4, A0,A1,A2,A3,A4);
  if constexpr (!DIR) { WAITVM(5); } else { WAITVM(0); }
  WRITESET(B0,B1,B2,B3,B4);
  barrier_lgkm();
  barrier_lgkm();
  barrier_lgkm();
#undef LSTEP
#undef WRITESET
#undef LOADSET
}

// ---------------- compute waves (waves 0..3 of scan blocks) ----------------
template <int DIR>
__device__ void compute_run(float* __restrict__ out, int n, int u,
                            const float* __restrict__ ring, float (*abuf)[SST]) {
  float* outn = out + (size_t)n * (T_STEPS + 1) * SST;
  float a[4] = {0.f, 0.f, 0.f, 0.f};

  {
    const float4 z = {0.f, 0.f, 0.f, 0.f};
    *(float4*)&abuf[0][4 * u] = z;
    const size_t t0 = DIR ? (size_t)T_STEPS : 0;
    ((float4*)(outn + t0 * SST))[u] = z;
  }
  barrier_lgkm();

  const float* rb = ring;
  int slot = 0;
  for (int s = 0; s < T_STEPS; ++s) {
    const int cur = s & 1, nxt = cur ^ 1;
    const float4* rv = (const float4*)(rb + 20 * u);
    const float4 q0 = rv[0], q1 = rv[1], q2 = rv[2], q3 = rv[3], q4 = rv[4];
    float fv[20];
    fv[0]=q0.x; fv[1]=q0.y; fv[2]=q0.z; fv[3]=q0.w;
    fv[4]=q1.x; fv[5]=q1.y; fv[6]=q1.z; fv[7]=q1.w;
    fv[8]=q2.x; fv[9]=q2.y; fv[10]=q2.z; fv[11]=q2.w;
    fv[12]=q3.x; fv[13]=q3.y; fv[14]=q3.z; fv[15]=q3.w;
    fv[16]=q4.x; fv[17]=q4.y; fv[18]=q4.z; fv[19]=q4.w;

    float na[4];
    if constexpr (!DIR) {
      const int q = u >> 2;
      const float p0 = abuf[cur][q];
      const float p1 = abuf[cur][q + 256];
      const float p2 = abuf[cur][q + 512];
      const float p3 = abuf[cur][q + 768];
#pragma unroll
      for (int j = 0; j < 4; ++j) {
        na[j] = lse5(fv[5*j] + a[j], fv[5*j+1] + p0, fv[5*j+2] + p1,
                     fv[5*j+3] + p2, fv[5*j+4] + p3);
        a[j] = na[j];
      }
      const float4 o = {na[0], na[1], na[2], na[3]};
      ((float4*)(outn + (size_t)(s + 1) * SST))[u] = o;
      *(float4*)&abuf[nxt][4 * u] = o;
    } else {
      const float4 pv = *(const float4*)&abuf[cur][4 * u];
      const float s0 = rb[5*u], s1 = rb[5*u+1280], s2 = rb[5*u+2560], s3 = rb[5*u+3840];
      const int t = T_STEPS - 1 - s;
      na[0] = lse5(s0 + a[0], fv[1] + pv.x, fv[6] + pv.y, fv[11] + pv.z, fv[16] + pv.w);
      na[1] = lse5(s1 + a[1], fv[2] + pv.x, fv[7] + pv.y, fv[12] + pv.z, fv[17] + pv.w);
      na[2] = lse5(s2 + a[2], fv[3] + pv.x, fv[8] + pv.y, fv[13] + pv.z, fv[18] + pv.w);
      na[3] = lse5(s3 + a[3], fv[4] + pv.x, fv[9] + pv.y, fv[14] + pv.z, fv[19] + pv.w);
#pragma unroll
      for (int j = 0; j < 4; ++j) {
        a[j] = na[j];
        outn[(size_t)t * SST + u + 256 * j] = na[j];
        abuf[nxt][u + 256 * j] = na[j];
      }
    }
    barrier_lgkm();
    slot = (slot + 1) & (NSLOT - 1);
    rb = ring + slot * ROW;
  }
}

// ---------------- prefetch army ----------------
// Pure readers: pull score slabs (640 KB, contiguous per t) HBM -> memory-side
// L3 just ahead of the scans. Results discarded (kept live via acc + an
// impossible-condition store to d_ws). Self-paced: army aggregate rate is at
// or below scan consumption, so its lead stays bounded; early/late prefetch
// affects only speed, never correctness.
__device__ void army_run(const float* __restrict__ scores, int t0, int dt,
                         float* __restrict__ ws) {
  const int tid = threadIdx.x;  // 0..511
  float acc0 = 0.f, acc1 = 0.f, acc2 = 0.f, acc3 = 0.f;
  for (int t = t0; (unsigned)t < (unsigned)T_STEPS; t += dt) {
    const float4* p = (const float4*)(scores + (size_t)t * STRIDE) + tid;
#pragma unroll
    for (int k = 0; k < 80; k += 4) {
      const float4 a = p[(k + 0) * 512];
      const float4 b = p[(k + 1) * 512];
      const float4 c = p[(k + 2) * 512];
      const float4 d = p[(k + 3) * 512];
      acc0 += a.x; acc1 += b.x; acc2 += c.x; acc3 += d.x;
    }
  }
  const float s = acc0 + acc1 + acc2 + acc3;
  if (s == 1e38f) ws[blockIdx.x] = s;   // never true for N(0,1) sums; keeps loads live
}

__global__ __launch_bounds__(512, 1) void mega(const float* __restrict__ scores,
                                               float* __restrict__ out0,
                                               float* __restrict__ bwdo,
                                               float* __restrict__ fposts,
                                               float* __restrict__ ws) {
  __shared__ float ring[NSLOT * ROW];   // 80 KB linear ring
  __shared__ float abuf[2][SST];        // 8 KB
  const int b = blockIdx.x;
  const int tid = threadIdx.x;

  if (b < NBATCH) {                     // fwd scan
    const float* base = scores + (size_t)b * ROW;
    if (tid < 256) compute_run<0>(fposts, b, tid, ring, abuf);
    else loader_run<0>(base, out0 + (size_t)b * T_STEPS * ROW,
                       (tid >> 6) - 4, tid & 63, ring);
  } else if (b < 2 * NBATCH) {          // bwd scan
    const int n = b - NBATCH;
    const float* base = scores + (size_t)n * ROW;
    if (tid < 256) compute_run<1>(bwdo, n, tid, ring, abuf);
    else loader_run<1>(base, nullptr, (tid >> 6) - 4, tid & 63, ring);
  } else if (b < 2 * NBATCH + ARMY_F) { // fwd prefetch army
    army_run(scores, b - 2 * NBATCH, ARMY_F, ws);
  } else {                              // bwd prefetch army
    army_run(scores, T_STEPS - 1 - (b - 2 * NBATCH - ARMY_F), -ARMY_B, ws);
  }
}

// One wave per row of 1024: posts = softmax(fwd + bwd), in place over fwd buffer.
__global__ __launch_bounds__(256) void posts_kernel(float* __restrict__ fp,
                                                    const float* __restrict__ bp) {
  const int lane = threadIdx.x & 63;
  const int wid  = threadIdx.x >> 6;
  const size_t row = (size_t)blockIdx.x * 4 + wid;
  float* f = fp + row * SST;
  const float* b = bp + row * SST;

  float x[16];
#pragma unroll
  for (int k = 0; k < 4; ++k) {
    const float4 fv = ((const float4*)f)[lane + 64 * k];
    const float4 bv = ((const float4*)b)[lane + 64 * k];
    x[4 * k + 0] = fv.x + bv.x;
    x[4 * k + 1] = fv.y + bv.y;
    x[4 * k + 2] = fv.z + bv.z;
    x[4 * k + 3] = fv.w + bv.w;
  }
  float m = x[0];
#pragma unroll
  for (int j = 1; j < 16; ++j) m = fmaxf(m, x[j]);
#pragma unroll
  for (int off = 32; off >= 1; off >>= 1) m = fmaxf(m, __shfl_xor(m, off));
  float ssum = 0.0f;
#pragma unroll
  for (int j = 0; j < 16; ++j) { x[j] = __expf(x[j] - m); ssum += x[j]; }
#pragma unroll
  for (int off = 32; off >= 1; off >>= 1) ssum += __shfl_xor(ssum, off);
  const float inv = 1.0f / ssum;
#pragma unroll
  for (int k = 0; k < 4; ++k) {
    float4 o;
    o.x = x[4 * k + 0] * inv;
    o.y = x[4 * k + 1] * inv;
    o.z = x[4 * k + 2] * inv;
    o.w = x[4 * k + 3] * inv;
    ((float4*)f)[lane + 64 * k] = o;
  }
}

extern "C" void kernel_launch(void* const* d_in, const int* in_sizes, int n_in,
                              void* d_out, int out_size, void* d_ws, size_t ws_size,
                              hipStream_t stream) {
  (void)in_sizes; (void)n_in; (void)ws_size; (void)out_size;
  const float* scores = (const float*)d_in[0];
  float* out = (float*)d_out;
  float* out0   = out;                                                  // (32,800,5120)
  float* bwdo   = out + (size_t)NBATCH * T_STEPS * ROW;                 // (32,801,1024)
  float* fposts = bwdo + (size_t)NBATCH * (T_STEPS + 1) * SST;          // (32,801,1024)

  mega<<<2 * NBATCH + ARMY_F + ARMY_B, 512, 0, stream>>>(scores, out0, bwdo, fposts,
                                                         (float*)d_ws);
  posts_kernel<<<(NBATCH * (T_STEPS + 1)) / 4, 256, 0, stream>>>(fposts, bwdo);
}